// Round 4
// baseline (3151.331 us; speedup 1.0000x reference)
//
#include <hip/hip_runtime.h>
#include <hip/hip_bf16.h>

#define F 64
#define VARIANTS 2
#define ACTS 6

// ---------------- CSR build ----------------

__global__ void k_hist(const int* __restrict__ dst, int* __restrict__ deg, int e) {
    int i = blockIdx.x * blockDim.x + threadIdx.x;
    if (i < e) atomicAdd(&deg[dst[i]], 1);
}

// block = 256 threads, each handles 4 elements (1024/block)
__global__ void k_scan1(const int* __restrict__ deg, int* __restrict__ rs,
                        int* __restrict__ bsum, int n) {
    __shared__ int sh[256];
    const int tid = threadIdx.x;
    const int base = blockIdx.x * 1024 + tid * 4;
    int v0 = (base + 0 < n) ? deg[base + 0] : 0;
    int v1 = (base + 1 < n) ? deg[base + 1] : 0;
    int v2 = (base + 2 < n) ? deg[base + 2] : 0;
    int v3 = (base + 3 < n) ? deg[base + 3] : 0;
    const int tsum = v0 + v1 + v2 + v3;
    sh[tid] = tsum;
    __syncthreads();
    for (int off = 1; off < 256; off <<= 1) {
        int t = (tid >= off) ? sh[tid - off] : 0;
        __syncthreads();
        sh[tid] += t;
        __syncthreads();
    }
    int excl = sh[tid] - tsum;  // exclusive prefix within block
    if (base + 0 < n) rs[base + 0] = excl; excl += v0;
    if (base + 1 < n) rs[base + 1] = excl; excl += v1;
    if (base + 2 < n) rs[base + 2] = excl; excl += v2;
    if (base + 3 < n) rs[base + 3] = excl;
    if (tid == 255) bsum[blockIdx.x] = sh[255];
}

__global__ void k_scan2(int* __restrict__ bsum, int nb) {
    __shared__ int sh[128];
    const int tid = threadIdx.x;
    int v = (tid < nb) ? bsum[tid] : 0;
    sh[tid] = v;
    __syncthreads();
    for (int off = 1; off < 128; off <<= 1) {
        int t = (tid >= off) ? sh[tid - off] : 0;
        __syncthreads();
        sh[tid] += t;
        __syncthreads();
    }
    if (tid < nb) bsum[tid] = sh[tid] - v;  // exclusive
}

__global__ void k_scan3(int* __restrict__ rs, const int* __restrict__ bsum,
                        int* __restrict__ cursor, int n, int total) {
    const int base = blockIdx.x * 1024 + threadIdx.x * 4;
    const int off = bsum[blockIdx.x];
    #pragma unroll
    for (int j = 0; j < 4; ++j) {
        int i = base + j;
        if (i < n) {
            int v = rs[i] + off;
            rs[i] = v;
            cursor[i] = v;
        }
    }
    if (blockIdx.x == 0 && threadIdx.x == 0) rs[n] = total;
}

__global__ void k_fill(const int* __restrict__ src, const int* __restrict__ dst,
                       int* __restrict__ cursor, int* __restrict__ csr, int e) {
    int i = blockIdx.x * blockDim.x + threadIdx.x;
    if (i < e) {
        int pos = atomicAdd(&cursor[dst[i]], 1);
        csr[pos] = src[i];
    }
}

// ---------------- GCN aggregate: agg[n][f] = sum over in-edges of h[src][f] ----------------
// one wave per node; lane = (neighbor subgroup 0..3, float4 chunk 0..15)
// each row read = global_load_dwordx4 across 16 lanes; 4 neighbor rows in flight / instr.
__global__ __launch_bounds__(256) void k_agg(
    const float* __restrict__ hin, const int* __restrict__ rs,
    const int* __restrict__ csr, float* __restrict__ agg, int n)
{
    const int tid = threadIdx.x;
    const int lane = tid & 63;
    const int nd = blockIdx.x * 4 + (tid >> 6);
    if (nd >= n) return;
    const int beg = rs[nd], end = rs[nd + 1];
    const int sub = lane >> 4;   // neighbor subgroup
    const int f4  = lane & 15;   // float4 chunk within row
    float ax = 0.f, ay = 0.f, az = 0.f, aw = 0.f;
    for (int cb = beg + sub; cb < end; cb += 4) {
        const int s = csr[cb];
        const float4 v = ((const float4*)(hin + (size_t)s * F))[f4];
        ax += v.x; ay += v.y; az += v.z; aw += v.w;
    }
    // reduce across the 4 subgroups (lanes differing in bits 4 and 5)
    #pragma unroll
    for (int o = 16; o <= 32; o <<= 1) {
        ax += __shfl_xor(ax, o);
        ay += __shfl_xor(ay, o);
        az += __shfl_xor(az, o);
        aw += __shfl_xor(aw, o);
    }
    if (sub == 0) {
        float4 r; r.x = ax; r.y = ay; r.z = az; r.w = aw;
        ((float4*)(agg + (size_t)nd * F))[f4] = r;
    }
}

// ---------------- fused linear: out = relu(agg@W + h@Wself + b) ----------------
// wave handles 8 nodes; lane = output feature; W columns live in VGPRs;
// activation rows read as float4 broadcast loads.
__global__ __launch_bounds__(256) void k_linear(
    const float* __restrict__ agg, const float* __restrict__ hin,
    const float* __restrict__ W, const float* __restrict__ Wself,
    const float* __restrict__ bias, float* __restrict__ out, int n)
{
    const int lane = threadIdx.x & 63;
    const int wv = blockIdx.x * 4 + (threadIdx.x >> 6);
    float wc[64], wsc[64];
    #pragma unroll
    for (int k = 0; k < 64; ++k) {
        wc[k]  = W[k * F + lane];
        wsc[k] = Wself[k * F + lane];
    }
    const float bf = bias[lane];
    const int base = wv * 8;
    #pragma unroll
    for (int t = 0; t < 8; ++t) {
        const int nd = base + t;
        if (nd < n) {
            const float4* __restrict__ ar4 = (const float4*)(agg + (size_t)nd * F);
            const float4* __restrict__ hr4 = (const float4*)(hin + (size_t)nd * F);
            float a = bf;
            #pragma unroll
            for (int q = 0; q < 16; ++q) {
                const float4 v = ar4[q];
                a = fmaf(v.x, wc[q * 4 + 0], a);
                a = fmaf(v.y, wc[q * 4 + 1], a);
                a = fmaf(v.z, wc[q * 4 + 2], a);
                a = fmaf(v.w, wc[q * 4 + 3], a);
            }
            #pragma unroll
            for (int q = 0; q < 16; ++q) {
                const float4 v = hr4[q];
                a = fmaf(v.x, wsc[q * 4 + 0], a);
                a = fmaf(v.y, wsc[q * 4 + 1], a);
                a = fmaf(v.z, wsc[q * 4 + 2], a);
                a = fmaf(v.w, wsc[q * 4 + 3], a);
            }
            out[(size_t)nd * F + lane] = fmaxf(a, 0.f);
        }
    }
}

// ---------------- decode: pp = logsigmoid(relu(cat @ Wd1 + bd1) @ Wd2 + bd2) ----------------
// cat = [feat[p] | feat[s] | feat[d]]  -> three K=64 passes with Wd1 column chunks in VGPRs.
// wave handles 8 triples; lane = hidden feature; rows read as float4 broadcast loads.
__global__ __launch_bounds__(256) void k_decode(
    const float* __restrict__ feat,
    const int* __restrict__ pi, const int* __restrict__ si, const int* __restrict__ di,
    const float* __restrict__ Wd1, const float* __restrict__ bd1,
    const float* __restrict__ Wd2, const float* __restrict__ bd2,
    float* __restrict__ pp, int nT)
{
    const int lane = threadIdx.x & 63;
    const int wv = blockIdx.x * 4 + (threadIdx.x >> 6);
    const int base = wv * 8;
    if (base >= nT) return;
    float acc[8];
    const float b0 = bd1[lane];
    #pragma unroll
    for (int t = 0; t < 8; ++t) acc[t] = b0;

    #pragma unroll
    for (int g = 0; g < 3; ++g) {
        const int* __restrict__ idx = (g == 0) ? pi : (g == 1) ? si : di;
        const float* __restrict__ Wg = Wd1 + (size_t)g * 64 * F;
        float wc[64];
        #pragma unroll
        for (int k = 0; k < 64; ++k) wc[k] = Wg[k * F + lane];
        #pragma unroll
        for (int t = 0; t < 8; ++t) {
            const int tri = base + t;
            if (tri < nT) {
                const int nd = idx[tri];  // wave-uniform
                const float4* __restrict__ row4 = (const float4*)(feat + (size_t)nd * F);
                float a = acc[t];
                #pragma unroll
                for (int q = 0; q < 16; ++q) {
                    const float4 v = row4[q];
                    a = fmaf(v.x, wc[q * 4 + 0], a);
                    a = fmaf(v.y, wc[q * 4 + 1], a);
                    a = fmaf(v.z, wc[q * 4 + 2], a);
                    a = fmaf(v.w, wc[q * 4 + 3], a);
                }
                acc[t] = a;
            }
        }
    }
    const float w2 = Wd2[lane];
    const float b2v = bd2[0];
    #pragma unroll
    for (int t = 0; t < 8; ++t) {
        const int tri = base + t;
        if (tri < nT) {
            float h = fmaxf(acc[t], 0.f);
            float v = h * w2;
            #pragma unroll
            for (int o = 32; o; o >>= 1) v += __shfl_xor(v, o);
            if (lane == 0) {
                float z = v + b2v;
                pp[tri] = fminf(z, 0.f) - log1pf(expf(-fabsf(z)));
            }
        }
    }
}

// ---------------- scatter / reduce / broadcast (sequential semantics, single block) ----------
__global__ __launch_bounds__(1024) void k_scatter(
    const float* __restrict__ pp, const int* __restrict__ p,
    float* __restrict__ pred, float* __restrict__ prev, int nP)
{
    __shared__ float wsum[16];
    __shared__ float s_tot;
    const int tid = threadIdx.x;
    // step 1: pred[p[i]] += pp[i]
    for (int i = tid; i < nP; i += 1024) atomicAdd(&pred[p[i]], pp[i]);
    __threadfence();
    __syncthreads();
    // step 2: s = sum_i pred[p[i]]  (after step-1 adds, duplicates included)
    float s = 0.f;
    for (int i = tid; i < nP; i += 1024)
        s += __hip_atomic_load(&pred[p[i]], __ATOMIC_RELAXED, __HIP_MEMORY_SCOPE_AGENT);
    #pragma unroll
    for (int o = 32; o; o >>= 1) s += __shfl_down(s, o);
    if ((tid & 63) == 0) wsum[tid >> 6] = s;
    __syncthreads();
    if (tid == 0) {
        float tot = 0.f;
        #pragma unroll
        for (int w = 0; w < 16; ++w) tot += wsum[w];
        tot += *prev;
        *prev = tot;
        s_tot = tot;
    }
    __syncthreads();
    const float tot = s_tot;
    __threadfence();
    // step 3: pred[p[i]] += prev_prob (duplicates add multiple times)
    for (int i = tid; i < nP; i += 1024) atomicAdd(&pred[p[i]], tot);
}

__global__ void k_addpred(const float* __restrict__ pred, float* __restrict__ out, int n) {
    int i = blockIdx.x * blockDim.x + threadIdx.x;
    if (i < n) out[i] += pred[i];
}

// ---------------- launch ----------------

extern "C" void kernel_launch(void* const* d_in, const int* in_sizes, int n_in,
                              void* d_out, int out_size, void* d_ws, size_t ws_size,
                              hipStream_t stream) {
    const float* x      = (const float*)d_in[0];
    const int*   eidx   = (const int*)d_in[1];
    const int*   places = (const int*)d_in[2];
    const int*   srcs   = (const int*)d_in[3];
    const int*   dsts   = (const int*)d_in[4];
    const float* W1     = (const float*)d_in[5];
    const float* Wself1 = (const float*)d_in[6];
    const float* b1     = (const float*)d_in[7];
    const float* W2     = (const float*)d_in[8];
    const float* Wself2 = (const float*)d_in[9];
    const float* b2     = (const float*)d_in[10];
    const float* Wd1    = (const float*)d_in[11];
    const float* bd1    = (const float*)d_in[12];
    const float* Wd2    = (const float*)d_in[13];
    const float* bd2    = (const float*)d_in[14];
    float* out          = (float*)d_out;

    const int N = in_sizes[0] / F;        // 100000
    const int E = in_sizes[1] / 2;        // 1600000
    const int P = in_sizes[2] / (VARIANTS * ACTS);  // 8192

    const int* edge_src = eidx;
    const int* edge_dst = eidx + E;

    // workspace carve (256B aligned)
    size_t off = 0;
    auto carve = [&](size_t bytes) -> void* {
        void* ptr = (char*)d_ws + off;
        off += (bytes + 255) & ~(size_t)255;
        return ptr;
    };
    int*   deg    = (int*)carve((size_t)N * 4);
    int*   rs     = (int*)carve((size_t)(N + 1) * 4);
    int*   cursor = (int*)carve((size_t)N * 4);
    int*   csr    = (int*)carve((size_t)E * 4);
    int*   bsum   = (int*)carve(128 * 4);
    float* feat0  = (float*)carve((size_t)N * F * 4);
    float* featB  = (float*)carve((size_t)N * F * 4);
    float* featC  = (float*)carve((size_t)N * F * 4);
    float* agg    = (float*)carve((size_t)N * F * 4);
    float* pp     = (float*)carve((size_t)P * 4);
    float* pred   = (float*)carve((size_t)N * 4);
    float* prev   = (float*)carve(256);
    (void)ws_size;

    const int nbScan   = (N + 1023) / 1024;                 // 98
    const int blkE     = (E + 255) / 256;
    const int blkAgg   = (N + 3) / 4;
    const int blkLin   = (N + 31) / 32;
    const int blkDec   = (P + 31) / 32;
    const int blkAdd   = (N + 255) / 256;

    (void)hipMemsetAsync(deg, 0, (size_t)N * 4, stream);
    (void)hipMemsetAsync(d_out, 0, (size_t)N * 4, stream);

    // CSR build
    k_hist <<<blkE, 256, 0, stream>>>(edge_dst, deg, E);
    k_scan1<<<nbScan, 256, 0, stream>>>(deg, rs, bsum, N);
    k_scan2<<<1, 128, 0, stream>>>(bsum, nbScan);
    k_scan3<<<nbScan, 256, 0, stream>>>(rs, bsum, cursor, N, E);
    k_fill <<<blkE, 256, 0, stream>>>(edge_src, edge_dst, cursor, csr, E);

    // first encoder: feat0 = relu(agg(x)@W1 + x@Wself1 + b1)
    k_agg   <<<blkAgg, 256, 0, stream>>>(x, rs, csr, agg, N);
    k_linear<<<blkLin, 256, 0, stream>>>(agg, x, W1, Wself1, b1, feat0, N);

    for (int v = 0; v < VARIANTS; ++v) {
        (void)hipMemsetAsync(pred, 0, (size_t)N * 4, stream);
        (void)hipMemsetAsync(prev, 0, 4, stream);
        const float* cur = feat0;
        for (int a = 0; a < ACTS; ++a) {
            const int* pi = places + ((size_t)v * ACTS + a) * P;
            const int* si = srcs   + ((size_t)v * ACTS + a) * P;
            const int* di = dsts   + ((size_t)v * ACTS + a) * P;
            k_decode<<<blkDec, 256, 0, stream>>>(cur, pi, si, di, Wd1, bd1, Wd2, bd2, pp, P);
            k_scatter<<<1, 1024, 0, stream>>>(pp, pi, pred, prev, P);
            if (a < ACTS - 1) {  // last GCN's output is never read -> skip
                float* nxt = (cur == featB) ? featC : featB;
                k_agg   <<<blkAgg, 256, 0, stream>>>(cur, rs, csr, agg, N);
                k_linear<<<blkLin, 256, 0, stream>>>(agg, cur, W2, Wself2, b2, nxt, N);
                cur = nxt;
            }
        }
        k_addpred<<<blkAdd, 256, 0, stream>>>(pred, out, N);
    }
}

// Round 8
// 1859.757 us; speedup vs baseline: 1.6945x; 1.6945x over previous
//
#include <hip/hip_runtime.h>
#include <hip/hip_bf16.h>

#define F 64
#define VARIANTS 2
#define ACTS 6

// ---------------- CSR build ----------------

__global__ void k_hist(const int* __restrict__ dst, int* __restrict__ deg, int e) {
    int i = blockIdx.x * blockDim.x + threadIdx.x;
    if (i < e) atomicAdd(&deg[dst[i]], 1);
}

// block = 256 threads, each handles 4 elements (1024/block)
__global__ void k_scan1(const int* __restrict__ deg, int* __restrict__ rs,
                        int* __restrict__ bsum, int n) {
    __shared__ int sh[256];
    const int tid = threadIdx.x;
    const int base = blockIdx.x * 1024 + tid * 4;
    int v0 = (base + 0 < n) ? deg[base + 0] : 0;
    int v1 = (base + 1 < n) ? deg[base + 1] : 0;
    int v2 = (base + 2 < n) ? deg[base + 2] : 0;
    int v3 = (base + 3 < n) ? deg[base + 3] : 0;
    const int tsum = v0 + v1 + v2 + v3;
    sh[tid] = tsum;
    __syncthreads();
    for (int off = 1; off < 256; off <<= 1) {
        int t = (tid >= off) ? sh[tid - off] : 0;
        __syncthreads();
        sh[tid] += t;
        __syncthreads();
    }
    int excl = sh[tid] - tsum;  // exclusive prefix within block
    if (base + 0 < n) rs[base + 0] = excl; excl += v0;
    if (base + 1 < n) rs[base + 1] = excl; excl += v1;
    if (base + 2 < n) rs[base + 2] = excl; excl += v2;
    if (base + 3 < n) rs[base + 3] = excl;
    if (tid == 255) bsum[blockIdx.x] = sh[255];
}

__global__ void k_scan2(int* __restrict__ bsum, int nb) {
    __shared__ int sh[128];
    const int tid = threadIdx.x;
    int v = (tid < nb) ? bsum[tid] : 0;
    sh[tid] = v;
    __syncthreads();
    for (int off = 1; off < 128; off <<= 1) {
        int t = (tid >= off) ? sh[tid - off] : 0;
        __syncthreads();
        sh[tid] += t;
        __syncthreads();
    }
    if (tid < nb) bsum[tid] = sh[tid] - v;  // exclusive
}

__global__ void k_scan3(int* __restrict__ rs, const int* __restrict__ bsum,
                        int* __restrict__ cursor, int n, int total) {
    const int base = blockIdx.x * 1024 + threadIdx.x * 4;
    const int off = bsum[blockIdx.x];
    #pragma unroll
    for (int j = 0; j < 4; ++j) {
        int i = base + j;
        if (i < n) {
            int v = rs[i] + off;
            rs[i] = v;
            cursor[i] = v;
        }
    }
    if (blockIdx.x == 0 && threadIdx.x == 0) rs[n] = total;
}

__global__ void k_fill(const int* __restrict__ src, const int* __restrict__ dst,
                       int* __restrict__ cursor, int* __restrict__ csr, int e) {
    int i = blockIdx.x * blockDim.x + threadIdx.x;
    if (i < e) {
        int pos = atomicAdd(&cursor[dst[i]], 1);
        csr[pos] = src[i];
    }
}

// ---------------- GCN aggregate: agg[n][f] = sum over in-edges of h[src][f] ----------------
// one wave per node; lane = (neighbor subgroup 0..3, float4 chunk 0..15)
__global__ __launch_bounds__(256) void k_agg(
    const float* __restrict__ hin, const int* __restrict__ rs,
    const int* __restrict__ csr, float* __restrict__ agg, int n)
{
    const int tid = threadIdx.x;
    const int lane = tid & 63;
    const int nd = blockIdx.x * 4 + (tid >> 6);
    if (nd >= n) return;
    const int beg = rs[nd], end = rs[nd + 1];
    const int sub = lane >> 4;   // neighbor subgroup
    const int f4  = lane & 15;   // float4 chunk within row
    float ax = 0.f, ay = 0.f, az = 0.f, aw = 0.f;
    for (int cb = beg + sub; cb < end; cb += 4) {
        const int s = csr[cb];
        const float4 v = ((const float4*)(hin + (size_t)s * F))[f4];
        ax += v.x; ay += v.y; az += v.z; aw += v.w;
    }
    // reduce across the 4 subgroups (lanes differing in bits 4 and 5)
    #pragma unroll
    for (int o = 16; o <= 32; o <<= 1) {
        ax += __shfl_xor(ax, o);
        ay += __shfl_xor(ay, o);
        az += __shfl_xor(az, o);
        aw += __shfl_xor(aw, o);
    }
    if (sub == 0) {
        float4 r; r.x = ax; r.y = ay; r.z = az; r.w = aw;
        ((float4*)(agg + (size_t)nd * F))[f4] = r;
    }
}

// ---------------- fused linear: out = relu(agg@W + h@Wself + b) ----------------
__global__ __launch_bounds__(256) void k_linear(
    const float* __restrict__ agg, const float* __restrict__ hin,
    const float* __restrict__ W, const float* __restrict__ Wself,
    const float* __restrict__ bias, float* __restrict__ out, int n)
{
    const int lane = threadIdx.x & 63;
    const int wv = blockIdx.x * 4 + (threadIdx.x >> 6);
    float wc[64], wsc[64];
    #pragma unroll
    for (int k = 0; k < 64; ++k) {
        wc[k]  = W[k * F + lane];
        wsc[k] = Wself[k * F + lane];
    }
    const float bf = bias[lane];
    const int base = wv * 8;
    #pragma unroll
    for (int t = 0; t < 8; ++t) {
        const int nd = base + t;
        if (nd < n) {
            const float4* __restrict__ ar4 = (const float4*)(agg + (size_t)nd * F);
            const float4* __restrict__ hr4 = (const float4*)(hin + (size_t)nd * F);
            float a = bf;
            #pragma unroll
            for (int q = 0; q < 16; ++q) {
                const float4 v = ar4[q];
                a = fmaf(v.x, wc[q * 4 + 0], a);
                a = fmaf(v.y, wc[q * 4 + 1], a);
                a = fmaf(v.z, wc[q * 4 + 2], a);
                a = fmaf(v.w, wc[q * 4 + 3], a);
            }
            #pragma unroll
            for (int q = 0; q < 16; ++q) {
                const float4 v = hr4[q];
                a = fmaf(v.x, wsc[q * 4 + 0], a);
                a = fmaf(v.y, wsc[q * 4 + 1], a);
                a = fmaf(v.z, wsc[q * 4 + 2], a);
                a = fmaf(v.w, wsc[q * 4 + 3], a);
            }
            out[(size_t)nd * F + lane] = fmaxf(a, 0.f);
        }
    }
}

// ---------------- decode (both variants in one launch) ----------------
// grid = 2 * bpv blocks; first bpv blocks -> v0, rest -> v1.
__global__ __launch_bounds__(256) void k_decode2(
    const float* __restrict__ feat,
    const int* __restrict__ places, const int* __restrict__ srcs, const int* __restrict__ dsts,
    int a, const float* __restrict__ Wd1, const float* __restrict__ bd1,
    const float* __restrict__ Wd2, const float* __restrict__ bd2,
    float* __restrict__ pp, int nT, int bpv)
{
    const int v   = blockIdx.x / bpv;
    const int blk = blockIdx.x % bpv;
    const size_t ofs = ((size_t)v * ACTS + a) * nT;
    const int* __restrict__ pi = places + ofs;
    const int* __restrict__ si = srcs   + ofs;
    const int* __restrict__ di = dsts   + ofs;
    float* __restrict__ ppv = pp + (size_t)v * nT;

    const int lane = threadIdx.x & 63;
    const int wv = blk * 4 + (threadIdx.x >> 6);
    const int base = wv * 8;
    if (base >= nT) return;
    float acc[8];
    const float b0 = bd1[lane];
    #pragma unroll
    for (int t = 0; t < 8; ++t) acc[t] = b0;

    #pragma unroll
    for (int g = 0; g < 3; ++g) {
        const int* __restrict__ idx = (g == 0) ? pi : (g == 1) ? si : di;
        const float* __restrict__ Wg = Wd1 + (size_t)g * 64 * F;
        float wc[64];
        #pragma unroll
        for (int k = 0; k < 64; ++k) wc[k] = Wg[k * F + lane];
        #pragma unroll
        for (int t = 0; t < 8; ++t) {
            const int tri = base + t;
            if (tri < nT) {
                const int nd = idx[tri];  // wave-uniform
                const float4* __restrict__ row4 = (const float4*)(feat + (size_t)nd * F);
                float a2 = acc[t];
                #pragma unroll
                for (int q = 0; q < 16; ++q) {
                    const float4 vv = row4[q];
                    a2 = fmaf(vv.x, wc[q * 4 + 0], a2);
                    a2 = fmaf(vv.y, wc[q * 4 + 1], a2);
                    a2 = fmaf(vv.z, wc[q * 4 + 2], a2);
                    a2 = fmaf(vv.w, wc[q * 4 + 3], a2);
                }
                acc[t] = a2;
            }
        }
    }
    const float w2 = Wd2[lane];
    const float b2v = bd2[0];
    #pragma unroll
    for (int t = 0; t < 8; ++t) {
        const int tri = base + t;
        if (tri < nT) {
            float h = fmaxf(acc[t], 0.f);
            float vv = h * w2;
            #pragma unroll
            for (int o = 32; o; o >>= 1) vv += __shfl_xor(vv, o);
            if (lane == 0) {
                float z = vv + b2v;
                ppv[tri] = fminf(z, 0.f) - log1pf(expf(-fabsf(z)));
            }
        }
    }
}

// ---------------- scatter / reduce / broadcast — both variants, one block each ----------
__global__ __launch_bounds__(1024) void k_scatter2(
    const float* __restrict__ pp, const int* __restrict__ places, int a,
    float* __restrict__ pred01, float* __restrict__ prev01, int nP, int strideN)
{
    const int v = blockIdx.x;
    const int* __restrict__ p = places + ((size_t)v * ACTS + a) * nP;
    const float* __restrict__ ppv = pp + (size_t)v * nP;
    float* __restrict__ pred = pred01 + (size_t)v * strideN;
    float* __restrict__ prev = prev01 + v;

    __shared__ float wsum[16];
    __shared__ float s_tot;
    const int tid = threadIdx.x;
    // step 1: pred[p[i]] += pp[i]
    for (int i = tid; i < nP; i += 1024) atomicAdd(&pred[p[i]], ppv[i]);
    __threadfence();
    __syncthreads();
    // step 2: s = sum_i pred[p[i]]  (after step-1 adds, duplicates included)
    float s = 0.f;
    for (int i = tid; i < nP; i += 1024)
        s += __hip_atomic_load(&pred[p[i]], __ATOMIC_RELAXED, __HIP_MEMORY_SCOPE_AGENT);
    #pragma unroll
    for (int o = 32; o; o >>= 1) s += __shfl_down(s, o);
    if ((tid & 63) == 0) wsum[tid >> 6] = s;
    __syncthreads();
    if (tid == 0) {
        float tot = 0.f;
        #pragma unroll
        for (int w = 0; w < 16; ++w) tot += wsum[w];
        tot += *prev;
        *prev = tot;
        s_tot = tot;
    }
    __syncthreads();
    const float tot = s_tot;
    __threadfence();
    // step 3: pred[p[i]] += prev_prob (duplicates add multiple times)
    for (int i = tid; i < nP; i += 1024) atomicAdd(&pred[p[i]], tot);
}

__global__ void k_sum2(const float* __restrict__ pred01, float* __restrict__ out,
                       int n, int strideN) {
    int i = blockIdx.x * blockDim.x + threadIdx.x;
    if (i < n) out[i] = pred01[i] + pred01[(size_t)strideN + i];
}

// ---------------- launch ----------------

extern "C" void kernel_launch(void* const* d_in, const int* in_sizes, int n_in,
                              void* d_out, int out_size, void* d_ws, size_t ws_size,
                              hipStream_t stream) {
    const float* x      = (const float*)d_in[0];
    const int*   eidx   = (const int*)d_in[1];
    const int*   places = (const int*)d_in[2];
    const int*   srcs   = (const int*)d_in[3];
    const int*   dsts   = (const int*)d_in[4];
    const float* W1     = (const float*)d_in[5];
    const float* Wself1 = (const float*)d_in[6];
    const float* b1     = (const float*)d_in[7];
    const float* W2     = (const float*)d_in[8];
    const float* Wself2 = (const float*)d_in[9];
    const float* b2     = (const float*)d_in[10];
    const float* Wd1    = (const float*)d_in[11];
    const float* bd1    = (const float*)d_in[12];
    const float* Wd2    = (const float*)d_in[13];
    const float* bd2    = (const float*)d_in[14];
    float* out          = (float*)d_out;

    const int N = in_sizes[0] / F;        // 100000
    const int E = in_sizes[1] / 2;        // 1600000
    const int P = in_sizes[2] / (VARIANTS * ACTS);  // 8192

    const int* edge_src = eidx;
    const int* edge_dst = eidx + E;

    // workspace carve (256B aligned)
    size_t off = 0;
    auto carve = [&](size_t bytes) -> void* {
        void* ptr = (char*)d_ws + off;
        off += (bytes + 255) & ~(size_t)255;
        return ptr;
    };
    int*   deg    = (int*)carve((size_t)N * 4);
    int*   rs     = (int*)carve((size_t)(N + 1) * 4);
    int*   cursor = (int*)carve((size_t)N * 4);
    int*   csr    = (int*)carve((size_t)E * 4);
    int*   bsum   = (int*)carve(128 * 4);
    float* feat0  = (float*)carve((size_t)N * F * 4);
    float* featB  = (float*)carve((size_t)N * F * 4);
    float* featC  = (float*)carve((size_t)N * F * 4);
    float* agg    = (float*)carve((size_t)N * F * 4);
    float* pp2    = (float*)carve((size_t)VARIANTS * P * 4);
    float* pred01 = (float*)carve((size_t)VARIANTS * N * 4);
    float* prev01 = (float*)carve(256);
    (void)ws_size;

    const int nbScan   = (N + 1023) / 1024;                 // 98
    const int blkE     = (E + 255) / 256;
    const int blkAgg   = (N + 3) / 4;
    const int blkLin   = (N + 31) / 32;
    const int bpv      = (P + 31) / 32;                     // 256 blocks per variant
    const int blkAdd   = (N + 255) / 256;

    (void)hipMemsetAsync(deg, 0, (size_t)N * 4, stream);
    (void)hipMemsetAsync(pred01, 0, (size_t)VARIANTS * N * 4, stream);
    (void)hipMemsetAsync(prev01, 0, 8, stream);

    // CSR build
    k_hist <<<blkE, 256, 0, stream>>>(edge_dst, deg, E);
    k_scan1<<<nbScan, 256, 0, stream>>>(deg, rs, bsum, N);
    k_scan2<<<1, 128, 0, stream>>>(bsum, nbScan);
    k_scan3<<<nbScan, 256, 0, stream>>>(rs, bsum, cursor, N, E);
    k_fill <<<blkE, 256, 0, stream>>>(edge_src, edge_dst, cursor, csr, E);

    // first encoder: feat0 = relu(agg(x)@W1 + x@Wself1 + b1)
    k_agg   <<<blkAgg, 256, 0, stream>>>(x, rs, csr, agg, N);
    k_linear<<<blkLin, 256, 0, stream>>>(agg, x, W1, Wself1, b1, feat0, N);

    // The second-encoder chain is variant-independent (feat resets to feat0 and
    // evolves with the same W2/Wself2/b2) -> compute it ONCE; per activity step
    // run both variants' decode+scatter on the shared feat.
    const float* cur = feat0;
    for (int a = 0; a < ACTS; ++a) {
        k_decode2<<<2 * bpv, 256, 0, stream>>>(cur, places, srcs, dsts, a,
                                               Wd1, bd1, Wd2, bd2, pp2, P, bpv);
        k_scatter2<<<2, 1024, 0, stream>>>(pp2, places, a, pred01, prev01, P, N);
        if (a < ACTS - 1) {  // last GCN's output is never read -> skip
            float* nxt = (cur == featB) ? featC : featB;
            k_agg   <<<blkAgg, 256, 0, stream>>>(cur, rs, csr, agg, N);
            k_linear<<<blkLin, 256, 0, stream>>>(agg, cur, W2, Wself2, b2, nxt, N);
            cur = nxt;
        }
    }
    k_sum2<<<blkAdd, 256, 0, stream>>>(pred01, out, N, N);
}

// Round 13
// 1851.617 us; speedup vs baseline: 1.7019x; 1.0044x over previous
//
#include <hip/hip_runtime.h>
#include <hip/hip_bf16.h>

#define F 64
#define VARIANTS 2
#define ACTS 6

// ---------------- CSR build ----------------

__global__ void k_hist(const int* __restrict__ dst, int* __restrict__ deg, int e) {
    int i = blockIdx.x * blockDim.x + threadIdx.x;
    if (i < e) atomicAdd(&deg[dst[i]], 1);
}

// block = 256 threads, each handles 4 elements (1024/block)
__global__ void k_scan1(const int* __restrict__ deg, int* __restrict__ rs,
                        int* __restrict__ bsum, int n) {
    __shared__ int sh[256];
    const int tid = threadIdx.x;
    const int base = blockIdx.x * 1024 + tid * 4;
    int v0 = (base + 0 < n) ? deg[base + 0] : 0;
    int v1 = (base + 1 < n) ? deg[base + 1] : 0;
    int v2 = (base + 2 < n) ? deg[base + 2] : 0;
    int v3 = (base + 3 < n) ? deg[base + 3] : 0;
    const int tsum = v0 + v1 + v2 + v3;
    sh[tid] = tsum;
    __syncthreads();
    for (int off = 1; off < 256; off <<= 1) {
        int t = (tid >= off) ? sh[tid - off] : 0;
        __syncthreads();
        sh[tid] += t;
        __syncthreads();
    }
    int excl = sh[tid] - tsum;  // exclusive prefix within block
    if (base + 0 < n) rs[base + 0] = excl; excl += v0;
    if (base + 1 < n) rs[base + 1] = excl; excl += v1;
    if (base + 2 < n) rs[base + 2] = excl; excl += v2;
    if (base + 3 < n) rs[base + 3] = excl;
    if (tid == 255) bsum[blockIdx.x] = sh[255];
}

__global__ void k_scan2(int* __restrict__ bsum, int nb) {
    __shared__ int sh[128];
    const int tid = threadIdx.x;
    int v = (tid < nb) ? bsum[tid] : 0;
    sh[tid] = v;
    __syncthreads();
    for (int off = 1; off < 128; off <<= 1) {
        int t = (tid >= off) ? sh[tid - off] : 0;
        __syncthreads();
        sh[tid] += t;
        __syncthreads();
    }
    if (tid < nb) bsum[tid] = sh[tid] - v;  // exclusive
}

__global__ void k_scan3(int* __restrict__ rs, const int* __restrict__ bsum,
                        int* __restrict__ cursor, int n, int total) {
    const int base = blockIdx.x * 1024 + threadIdx.x * 4;
    const int off = bsum[blockIdx.x];
    #pragma unroll
    for (int j = 0; j < 4; ++j) {
        int i = base + j;
        if (i < n) {
            int v = rs[i] + off;
            rs[i] = v;
            cursor[i] = v;
        }
    }
    if (blockIdx.x == 0 && threadIdx.x == 0) rs[n] = total;
}

// split-range fill so each dispatch is ~64 µs (surfaces other kernels in top-5)
__global__ void k_fill(const int* __restrict__ src, const int* __restrict__ dst,
                       int* __restrict__ cursor, int* __restrict__ csr, int e0, int e1) {
    int i = e0 + blockIdx.x * blockDim.x + threadIdx.x;
    if (i < e1) {
        int pos = atomicAdd(&cursor[dst[i]], 1);
        csr[pos] = src[i];
    }
}

// ---------------- GCN aggregate: agg[n][f] = sum over in-edges of h[src][f] ----------------
// one wave per node; lane = (neighbor subgroup 0..3, float4 chunk 0..15)
__global__ __launch_bounds__(256) void k_agg(
    const float* __restrict__ hin, const int* __restrict__ rs,
    const int* __restrict__ csr, float* __restrict__ agg, int n)
{
    const int tid = threadIdx.x;
    const int lane = tid & 63;
    const int nd = blockIdx.x * 4 + (tid >> 6);
    if (nd >= n) return;
    const int beg = rs[nd], end = rs[nd + 1];
    const int sub = lane >> 4;   // neighbor subgroup
    const int f4  = lane & 15;   // float4 chunk within row
    float ax = 0.f, ay = 0.f, az = 0.f, aw = 0.f;
    for (int cb = beg + sub; cb < end; cb += 4) {
        const int s = csr[cb];
        const float4 v = ((const float4*)(hin + (size_t)s * F))[f4];
        ax += v.x; ay += v.y; az += v.z; aw += v.w;
    }
    // reduce across the 4 subgroups (lanes differing in bits 4 and 5)
    #pragma unroll
    for (int o = 16; o <= 32; o <<= 1) {
        ax += __shfl_xor(ax, o);
        ay += __shfl_xor(ay, o);
        az += __shfl_xor(az, o);
        aw += __shfl_xor(aw, o);
    }
    if (sub == 0) {
        float4 r; r.x = ax; r.y = ay; r.z = az; r.w = aw;
        ((float4*)(agg + (size_t)nd * F))[f4] = r;
    }
}

// ---------------- fused linear: out = relu(agg@W + h@Wself + b) ----------------
__global__ __launch_bounds__(256) void k_linear(
    const float* __restrict__ agg, const float* __restrict__ hin,
    const float* __restrict__ W, const float* __restrict__ Wself,
    const float* __restrict__ bias, float* __restrict__ out, int n)
{
    const int lane = threadIdx.x & 63;
    const int wv = blockIdx.x * 4 + (threadIdx.x >> 6);
    float wc[64], wsc[64];
    #pragma unroll
    for (int k = 0; k < 64; ++k) {
        wc[k]  = W[k * F + lane];
        wsc[k] = Wself[k * F + lane];
    }
    const float bf = bias[lane];
    const int base = wv * 8;
    #pragma unroll
    for (int t = 0; t < 8; ++t) {
        const int nd = base + t;
        if (nd < n) {
            const float4* __restrict__ ar4 = (const float4*)(agg + (size_t)nd * F);
            const float4* __restrict__ hr4 = (const float4*)(hin + (size_t)nd * F);
            float a = bf;
            #pragma unroll
            for (int q = 0; q < 16; ++q) {
                const float4 v = ar4[q];
                a = fmaf(v.x, wc[q * 4 + 0], a);
                a = fmaf(v.y, wc[q * 4 + 1], a);
                a = fmaf(v.z, wc[q * 4 + 2], a);
                a = fmaf(v.w, wc[q * 4 + 3], a);
            }
            #pragma unroll
            for (int q = 0; q < 16; ++q) {
                const float4 v = hr4[q];
                a = fmaf(v.x, wsc[q * 4 + 0], a);
                a = fmaf(v.y, wsc[q * 4 + 1], a);
                a = fmaf(v.z, wsc[q * 4 + 2], a);
                a = fmaf(v.w, wsc[q * 4 + 3], a);
            }
            out[(size_t)nd * F + lane] = fmaxf(a, 0.f);
        }
    }
}

// ---------------- decode (both variants in one launch) ----------------
// grid = 2 * bpv blocks; writes pp_all[v][a][P]
__global__ __launch_bounds__(256) void k_decode2(
    const float* __restrict__ feat,
    const int* __restrict__ places, const int* __restrict__ srcs, const int* __restrict__ dsts,
    int a, const float* __restrict__ Wd1, const float* __restrict__ bd1,
    const float* __restrict__ Wd2, const float* __restrict__ bd2,
    float* __restrict__ pp_all, int nT, int bpv)
{
    const int v   = blockIdx.x / bpv;
    const int blk = blockIdx.x % bpv;
    const size_t ofs = ((size_t)v * ACTS + a) * nT;
    const int* __restrict__ pi = places + ofs;
    const int* __restrict__ si = srcs   + ofs;
    const int* __restrict__ di = dsts   + ofs;
    float* __restrict__ ppv = pp_all + ofs;

    const int lane = threadIdx.x & 63;
    const int wv = blk * 4 + (threadIdx.x >> 6);
    const int base = wv * 8;
    if (base >= nT) return;
    float acc[8];
    const float b0 = bd1[lane];
    #pragma unroll
    for (int t = 0; t < 8; ++t) acc[t] = b0;

    #pragma unroll
    for (int g = 0; g < 3; ++g) {
        const int* __restrict__ idx = (g == 0) ? pi : (g == 1) ? si : di;
        const float* __restrict__ Wg = Wd1 + (size_t)g * 64 * F;
        float wc[64];
        #pragma unroll
        for (int k = 0; k < 64; ++k) wc[k] = Wg[k * F + lane];
        #pragma unroll
        for (int t = 0; t < 8; ++t) {
            const int tri = base + t;
            if (tri < nT) {
                const int nd = idx[tri];  // wave-uniform
                const float4* __restrict__ row4 = (const float4*)(feat + (size_t)nd * F);
                float a2 = acc[t];
                #pragma unroll
                for (int q = 0; q < 16; ++q) {
                    const float4 vv = row4[q];
                    a2 = fmaf(vv.x, wc[q * 4 + 0], a2);
                    a2 = fmaf(vv.y, wc[q * 4 + 1], a2);
                    a2 = fmaf(vv.z, wc[q * 4 + 2], a2);
                    a2 = fmaf(vv.w, wc[q * 4 + 3], a2);
                }
                acc[t] = a2;
            }
        }
    }
    const float w2 = Wd2[lane];
    const float b2v = bd2[0];
    #pragma unroll
    for (int t = 0; t < 8; ++t) {
        const int tri = base + t;
        if (tri < nT) {
            float h = fmaxf(acc[t], 0.f);
            float vv = h * w2;
            #pragma unroll
            for (int o = 32; o; o >>= 1) vv += __shfl_xor(vv, o);
            if (lane == 0) {
                float z = vv + b2v;
                ppv[tri] = fminf(z, 0.f) - log1pf(expf(-fabsf(z)));
            }
        }
    }
}

// ---------------- all 12 scatter steps in one kernel ----------------
// block v handles variant v's 6 sequential activities (pred/prev private to block)
__global__ __launch_bounds__(1024) void k_scatter_all(
    const float* __restrict__ pp_all, const int* __restrict__ places,
    float* __restrict__ pred01, int nP, int strideN)
{
    const int v = blockIdx.x;
    float* __restrict__ pred = pred01 + (size_t)v * strideN;
    __shared__ float wsum[16];
    __shared__ float s_tot;
    __shared__ float s_prev;
    const int tid = threadIdx.x;
    if (tid == 0) s_prev = 0.f;
    __syncthreads();

    for (int a = 0; a < ACTS; ++a) {
        const size_t ofs = ((size_t)v * ACTS + a) * nP;
        const int* __restrict__ p = places + ofs;
        const float* __restrict__ ppv = pp_all + ofs;
        // step 1: pred[p[i]] += pp[i]
        for (int i = tid; i < nP; i += 1024) atomicAdd(&pred[p[i]], ppv[i]);
        __threadfence();
        __syncthreads();
        // step 2: s = sum_i pred[p[i]] (after step-1 adds, duplicates included)
        float s = 0.f;
        for (int i = tid; i < nP; i += 1024)
            s += __hip_atomic_load(&pred[p[i]], __ATOMIC_RELAXED, __HIP_MEMORY_SCOPE_AGENT);
        #pragma unroll
        for (int o = 32; o; o >>= 1) s += __shfl_down(s, o);
        if ((tid & 63) == 0) wsum[tid >> 6] = s;
        __syncthreads();
        if (tid == 0) {
            float tot = 0.f;
            #pragma unroll
            for (int w = 0; w < 16; ++w) tot += wsum[w];
            tot += s_prev;
            s_prev = tot;
            s_tot = tot;
        }
        __syncthreads();
        const float tot = s_tot;
        __threadfence();
        // step 3: pred[p[i]] += prev_prob (duplicates add multiple times)
        for (int i = tid; i < nP; i += 1024) atomicAdd(&pred[p[i]], tot);
        __threadfence();
        __syncthreads();
    }
}

__global__ void k_sum2(const float* __restrict__ pred01, float* __restrict__ out,
                       int n, int strideN) {
    int i = blockIdx.x * blockDim.x + threadIdx.x;
    if (i < n) out[i] = pred01[i] + pred01[(size_t)strideN + i];
}

// ---------------- launch ----------------

extern "C" void kernel_launch(void* const* d_in, const int* in_sizes, int n_in,
                              void* d_out, int out_size, void* d_ws, size_t ws_size,
                              hipStream_t stream) {
    const float* x      = (const float*)d_in[0];
    const int*   eidx   = (const int*)d_in[1];
    const int*   places = (const int*)d_in[2];
    const int*   srcs   = (const int*)d_in[3];
    const int*   dsts   = (const int*)d_in[4];
    const float* W1     = (const float*)d_in[5];
    const float* Wself1 = (const float*)d_in[6];
    const float* b1     = (const float*)d_in[7];
    const float* W2     = (const float*)d_in[8];
    const float* Wself2 = (const float*)d_in[9];
    const float* b2     = (const float*)d_in[10];
    const float* Wd1    = (const float*)d_in[11];
    const float* bd1    = (const float*)d_in[12];
    const float* Wd2    = (const float*)d_in[13];
    const float* bd2    = (const float*)d_in[14];
    float* out          = (float*)d_out;

    const int N = in_sizes[0] / F;        // 100000
    const int E = in_sizes[1] / 2;        // 1600000
    const int P = in_sizes[2] / (VARIANTS * ACTS);  // 8192

    const int* edge_src = eidx;
    const int* edge_dst = eidx + E;

    // workspace carve (256B aligned); deg+pred01 first -> one zeroing memset
    size_t off = 0;
    auto carve = [&](size_t bytes) -> void* {
        void* ptr = (char*)d_ws + off;
        off += (bytes + 255) & ~(size_t)255;
        return ptr;
    };
    int*   deg    = (int*)carve((size_t)N * 4);
    float* pred01 = (float*)carve((size_t)VARIANTS * N * 4);
    const size_t zbytes = off;                       // zero deg + pred01 in one memset
    int*   rs     = (int*)carve((size_t)(N + 1) * 4);
    int*   cursor = (int*)carve((size_t)N * 4);
    int*   csr    = (int*)carve((size_t)E * 4);
    int*   bsum   = (int*)carve(128 * 4);
    float* feat0  = (float*)carve((size_t)N * F * 4);
    float* featB  = (float*)carve((size_t)N * F * 4);
    float* featC  = (float*)carve((size_t)N * F * 4);
    float* agg    = (float*)carve((size_t)N * F * 4);
    float* pp_all = (float*)carve((size_t)VARIANTS * ACTS * P * 4);
    (void)ws_size;

    const int nbScan   = (N + 1023) / 1024;                 // 98
    const int Ehalf    = E / 2;
    const int blkEh    = (Ehalf + 255) / 256;
    const int blkE2    = (E - Ehalf + 255) / 256;
    const int blkAgg   = (N + 3) / 4;
    const int blkLin   = (N + 31) / 32;
    const int bpv      = (P + 31) / 32;                     // 256 blocks per variant
    const int blkAdd   = (N + 255) / 256;

    (void)hipMemsetAsync(d_ws, 0, zbytes, stream);

    // CSR build (fill split in two for profiler attribution of other kernels)
    k_hist <<<(E + 255) / 256, 256, 0, stream>>>(edge_dst, deg, E);
    k_scan1<<<nbScan, 256, 0, stream>>>(deg, rs, bsum, N);
    k_scan2<<<1, 128, 0, stream>>>(bsum, nbScan);
    k_scan3<<<nbScan, 256, 0, stream>>>(rs, bsum, cursor, N, E);
    k_fill <<<blkEh, 256, 0, stream>>>(edge_src, edge_dst, cursor, csr, 0, Ehalf);
    k_fill <<<blkE2, 256, 0, stream>>>(edge_src, edge_dst, cursor, csr, Ehalf, E);

    // first encoder: feat0 = relu(agg(x)@W1 + x@Wself1 + b1)
    k_agg   <<<blkAgg, 256, 0, stream>>>(x, rs, csr, agg, N);
    k_linear<<<blkLin, 256, 0, stream>>>(agg, x, W1, Wself1, b1, feat0, N);

    // Second-encoder chain is variant-independent -> compute once; decode both
    // variants per activity; scatters are fully decoupled -> run all at the end.
    const float* cur = feat0;
    for (int a = 0; a < ACTS; ++a) {
        k_decode2<<<2 * bpv, 256, 0, stream>>>(cur, places, srcs, dsts, a,
                                               Wd1, bd1, Wd2, bd2, pp_all, P, bpv);
        if (a < ACTS - 1) {  // last GCN's output is never read -> skip
            float* nxt = (cur == featB) ? featC : featB;
            k_agg   <<<blkAgg, 256, 0, stream>>>(cur, rs, csr, agg, N);
            k_linear<<<blkLin, 256, 0, stream>>>(agg, cur, W2, Wself2, b2, nxt, N);
            cur = nxt;
        }
    }
    k_scatter_all<<<VARIANTS, 1024, 0, stream>>>(pp_all, places, pred01, P, N);
    k_sum2<<<blkAdd, 256, 0, stream>>>(pred01, out, N, N);
}

// Round 14
// 1596.817 us; speedup vs baseline: 1.9735x; 1.1596x over previous
//
#include <hip/hip_runtime.h>
#include <hip/hip_bf16.h>

#define F 64
#define VARIANTS 2
#define ACTS 6
#define NVA (VARIANTS * ACTS)

// ---------------- CSR build ----------------

__global__ void k_hist(const int* __restrict__ dst, int* __restrict__ deg, int e) {
    int i = blockIdx.x * blockDim.x + threadIdx.x;
    if (i < e) atomicAdd(&deg[dst[i]], 1);
}

__global__ void k_scan1(const int* __restrict__ deg, int* __restrict__ rs,
                        int* __restrict__ bsum, int n) {
    __shared__ int sh[256];
    const int tid = threadIdx.x;
    const int base = blockIdx.x * 1024 + tid * 4;
    int v0 = (base + 0 < n) ? deg[base + 0] : 0;
    int v1 = (base + 1 < n) ? deg[base + 1] : 0;
    int v2 = (base + 2 < n) ? deg[base + 2] : 0;
    int v3 = (base + 3 < n) ? deg[base + 3] : 0;
    const int tsum = v0 + v1 + v2 + v3;
    sh[tid] = tsum;
    __syncthreads();
    for (int off = 1; off < 256; off <<= 1) {
        int t = (tid >= off) ? sh[tid - off] : 0;
        __syncthreads();
        sh[tid] += t;
        __syncthreads();
    }
    int excl = sh[tid] - tsum;  // exclusive prefix within block
    if (base + 0 < n) rs[base + 0] = excl; excl += v0;
    if (base + 1 < n) rs[base + 1] = excl; excl += v1;
    if (base + 2 < n) rs[base + 2] = excl; excl += v2;
    if (base + 3 < n) rs[base + 3] = excl;
    if (tid == 255) bsum[blockIdx.x] = sh[255];
}

__global__ void k_scan2(int* __restrict__ bsum, int nb) {
    __shared__ int sh[128];
    const int tid = threadIdx.x;
    int v = (tid < nb) ? bsum[tid] : 0;
    sh[tid] = v;
    __syncthreads();
    for (int off = 1; off < 128; off <<= 1) {
        int t = (tid >= off) ? sh[tid - off] : 0;
        __syncthreads();
        sh[tid] += t;
        __syncthreads();
    }
    if (tid < nb) bsum[tid] = sh[tid] - v;  // exclusive
}

__global__ void k_scan3(int* __restrict__ rs, const int* __restrict__ bsum,
                        int* __restrict__ cursor, int n, int total) {
    const int base = blockIdx.x * 1024 + threadIdx.x * 4;
    const int off = bsum[blockIdx.x];
    #pragma unroll
    for (int j = 0; j < 4; ++j) {
        int i = base + j;
        if (i < n) {
            int v = rs[i] + off;
            rs[i] = v;
            cursor[i] = v;
        }
    }
    if (blockIdx.x == 0 && threadIdx.x == 0) rs[n] = total;
}

// split-range fill (two ~64 µs dispatches for profiler attribution)
__global__ void k_fill(const int* __restrict__ src, const int* __restrict__ dst,
                       int* __restrict__ cursor, int* __restrict__ csr, int e0, int e1) {
    int i = e0 + blockIdx.x * blockDim.x + threadIdx.x;
    if (i < e1) {
        int pos = atomicAdd(&cursor[dst[i]], 1);
        csr[pos] = src[i];
    }
}

// ---------------- GCN aggregate ----------------
__global__ __launch_bounds__(256) void k_agg(
    const float* __restrict__ hin, const int* __restrict__ rs,
    const int* __restrict__ csr, float* __restrict__ agg, int n)
{
    const int tid = threadIdx.x;
    const int lane = tid & 63;
    const int nd = blockIdx.x * 4 + (tid >> 6);
    if (nd >= n) return;
    const int beg = rs[nd], end = rs[nd + 1];
    const int sub = lane >> 4;   // neighbor subgroup
    const int f4  = lane & 15;   // float4 chunk within row
    float ax = 0.f, ay = 0.f, az = 0.f, aw = 0.f;
    for (int cb = beg + sub; cb < end; cb += 4) {
        const int s = csr[cb];
        const float4 v = ((const float4*)(hin + (size_t)s * F))[f4];
        ax += v.x; ay += v.y; az += v.z; aw += v.w;
    }
    #pragma unroll
    for (int o = 16; o <= 32; o <<= 1) {
        ax += __shfl_xor(ax, o);
        ay += __shfl_xor(ay, o);
        az += __shfl_xor(az, o);
        aw += __shfl_xor(aw, o);
    }
    if (sub == 0) {
        float4 r; r.x = ax; r.y = ay; r.z = az; r.w = aw;
        ((float4*)(agg + (size_t)nd * F))[f4] = r;
    }
}

// ---------------- fused linear ----------------
__global__ __launch_bounds__(256) void k_linear(
    const float* __restrict__ agg, const float* __restrict__ hin,
    const float* __restrict__ W, const float* __restrict__ Wself,
    const float* __restrict__ bias, float* __restrict__ out, int n)
{
    const int lane = threadIdx.x & 63;
    const int wv = blockIdx.x * 4 + (threadIdx.x >> 6);
    float wc[64], wsc[64];
    #pragma unroll
    for (int k = 0; k < 64; ++k) {
        wc[k]  = W[k * F + lane];
        wsc[k] = Wself[k * F + lane];
    }
    const float bf = bias[lane];
    const int base = wv * 8;
    #pragma unroll
    for (int t = 0; t < 8; ++t) {
        const int nd = base + t;
        if (nd < n) {
            const float4* __restrict__ ar4 = (const float4*)(agg + (size_t)nd * F);
            const float4* __restrict__ hr4 = (const float4*)(hin + (size_t)nd * F);
            float a = bf;
            #pragma unroll
            for (int q = 0; q < 16; ++q) {
                const float4 v = ar4[q];
                a = fmaf(v.x, wc[q * 4 + 0], a);
                a = fmaf(v.y, wc[q * 4 + 1], a);
                a = fmaf(v.z, wc[q * 4 + 2], a);
                a = fmaf(v.w, wc[q * 4 + 3], a);
            }
            #pragma unroll
            for (int q = 0; q < 16; ++q) {
                const float4 v = hr4[q];
                a = fmaf(v.x, wsc[q * 4 + 0], a);
                a = fmaf(v.y, wsc[q * 4 + 1], a);
                a = fmaf(v.z, wsc[q * 4 + 2], a);
                a = fmaf(v.w, wsc[q * 4 + 3], a);
            }
            out[(size_t)nd * F + lane] = fmaxf(a, 0.f);
        }
    }
}

// ---------------- decode (both variants in one launch) ----------------
__global__ __launch_bounds__(256) void k_decode2(
    const float* __restrict__ feat,
    const int* __restrict__ places, const int* __restrict__ srcs, const int* __restrict__ dsts,
    int a, const float* __restrict__ Wd1, const float* __restrict__ bd1,
    const float* __restrict__ Wd2, const float* __restrict__ bd2,
    float* __restrict__ pp_all, int nT, int bpv)
{
    const int v   = blockIdx.x / bpv;
    const int blk = blockIdx.x % bpv;
    const size_t ofs = ((size_t)v * ACTS + a) * nT;
    const int* __restrict__ pi = places + ofs;
    const int* __restrict__ si = srcs   + ofs;
    const int* __restrict__ di = dsts   + ofs;
    float* __restrict__ ppv = pp_all + ofs;

    const int lane = threadIdx.x & 63;
    const int wv = blk * 4 + (threadIdx.x >> 6);
    const int base = wv * 8;
    if (base >= nT) return;
    float acc[8];
    const float b0 = bd1[lane];
    #pragma unroll
    for (int t = 0; t < 8; ++t) acc[t] = b0;

    #pragma unroll
    for (int g = 0; g < 3; ++g) {
        const int* __restrict__ idx = (g == 0) ? pi : (g == 1) ? si : di;
        const float* __restrict__ Wg = Wd1 + (size_t)g * 64 * F;
        float wc[64];
        #pragma unroll
        for (int k = 0; k < 64; ++k) wc[k] = Wg[k * F + lane];
        #pragma unroll
        for (int t = 0; t < 8; ++t) {
            const int tri = base + t;
            if (tri < nT) {
                const int nd = idx[tri];  // wave-uniform
                const float4* __restrict__ row4 = (const float4*)(feat + (size_t)nd * F);
                float a2 = acc[t];
                #pragma unroll
                for (int q = 0; q < 16; ++q) {
                    const float4 vv = row4[q];
                    a2 = fmaf(vv.x, wc[q * 4 + 0], a2);
                    a2 = fmaf(vv.y, wc[q * 4 + 1], a2);
                    a2 = fmaf(vv.z, wc[q * 4 + 2], a2);
                    a2 = fmaf(vv.w, wc[q * 4 + 3], a2);
                }
                acc[t] = a2;
            }
        }
    }
    const float w2 = Wd2[lane];
    const float b2v = bd2[0];
    #pragma unroll
    for (int t = 0; t < 8; ++t) {
        const int tri = base + t;
        if (tri < nT) {
            float h = fmaxf(acc[t], 0.f);
            float vv = h * w2;
            #pragma unroll
            for (int o = 32; o; o >>= 1) vv += __shfl_xor(vv, o);
            if (lane == 0) {
                float z = vv + b2v;
                ppv[tri] = fminf(z, 0.f) - log1pf(expf(-fabsf(z)));
            }
        }
    }
}

// ---------------- scatter pipeline (algebraic, fully parallel) ----------------
// The reference scatter chain is linear in pred:
//   s_a   = sum_{b<=a} A_{a,b} + sum_{b<a} C_{a,b} * prev_b
//   prev_a = prev_{a-1} + s_a
//   pred(n) = sum_a [ S_a(n) + c_a(n) * prev_a ]
// with S_a(n)=scatter-sum of pp_a, c_a(n)=occurrence counts,
//      A_{a,b}=sum_i S_b(p_a[i]), C_{a,b}=sum_i c_b(p_a[i]).

// scatter images S[va][n], counts c[va][n]
__global__ void k_sc_scatter(const float* __restrict__ pp_all, const int* __restrict__ places,
                             float* __restrict__ S, float* __restrict__ c, int nP, int n) {
    int gid = blockIdx.x * blockDim.x + threadIdx.x;
    if (gid < NVA * nP) {
        int va = gid / nP;
        int p = places[gid];
        atomicAdd(&S[(size_t)va * n + p], pp_all[gid]);
        atomicAdd(&c[(size_t)va * n + p], 1.0f);
    }
}

// A and C matrices: one block per (v,a,b); idle if b > a
__global__ __launch_bounds__(256) void k_sc_mats(
    const float* __restrict__ S, const float* __restrict__ c,
    const int* __restrict__ places,
    float* __restrict__ matsA, float* __restrict__ matsC, int nP, int n)
{
    const int bx = blockIdx.x;          // v*36 + a*6 + b
    const int v = bx / 36;
    const int a = (bx / 6) % 6;
    const int b = bx % 6;
    if (b > a) return;
    const int* __restrict__ p = places + (size_t)(v * ACTS + a) * nP;
    const float* __restrict__ Sb = S + (size_t)(v * ACTS + b) * n;
    const float* __restrict__ cb = c + (size_t)(v * ACTS + b) * n;
    float sS = 0.f, sC = 0.f;
    for (int i = threadIdx.x; i < nP; i += 256) {
        const int idx = p[i];
        sS += Sb[idx];
        sC += cb[idx];
    }
    __shared__ float shS[4], shC[4];
    #pragma unroll
    for (int o = 32; o; o >>= 1) { sS += __shfl_down(sS, o); sC += __shfl_down(sC, o); }
    const int lane = threadIdx.x & 63, w = threadIdx.x >> 6;
    if (lane == 0) { shS[w] = sS; shC[w] = sC; }
    __syncthreads();
    if (threadIdx.x == 0) {
        matsA[bx] = shS[0] + shS[1] + shS[2] + shS[3];
        matsC[bx] = shC[0] + shC[1] + shC[2] + shC[3];
    }
}

// scalar recurrence: 12 values, 1 thread per variant
__global__ void k_sc_prev(const float* __restrict__ matsA, const float* __restrict__ matsC,
                          float* __restrict__ prevs) {
    const int v = threadIdx.x;
    if (v >= VARIANTS) return;
    float pl[ACTS];
    float prev = 0.f;
    #pragma unroll
    for (int a = 0; a < ACTS; ++a) {
        float s = 0.f;
        #pragma unroll
        for (int b = 0; b < ACTS; ++b) {
            if (b <= a) s += matsA[v * 36 + a * 6 + b];
            if (b < a)  s += matsC[v * 36 + a * 6 + b] * pl[b];
        }
        prev += s;
        pl[a] = prev;
        prevs[v * ACTS + a] = prev;
    }
}

// out[n] = sum_va [ S_va(n) + c_va(n) * prev_va ]
__global__ void k_out(const float* __restrict__ S, const float* __restrict__ c,
                      const float* __restrict__ prevs, float* __restrict__ out, int n) {
    int i = blockIdx.x * blockDim.x + threadIdx.x;
    if (i < n) {
        float acc = 0.f;
        #pragma unroll
        for (int va = 0; va < NVA; ++va)
            acc += S[(size_t)va * n + i] + c[(size_t)va * n + i] * prevs[va];
        out[i] = acc;
    }
}

// ---------------- launch ----------------

extern "C" void kernel_launch(void* const* d_in, const int* in_sizes, int n_in,
                              void* d_out, int out_size, void* d_ws, size_t ws_size,
                              hipStream_t stream) {
    const float* x      = (const float*)d_in[0];
    const int*   eidx   = (const int*)d_in[1];
    const int*   places = (const int*)d_in[2];
    const int*   srcs   = (const int*)d_in[3];
    const int*   dsts   = (const int*)d_in[4];
    const float* W1     = (const float*)d_in[5];
    const float* Wself1 = (const float*)d_in[6];
    const float* b1     = (const float*)d_in[7];
    const float* W2     = (const float*)d_in[8];
    const float* Wself2 = (const float*)d_in[9];
    const float* b2     = (const float*)d_in[10];
    const float* Wd1    = (const float*)d_in[11];
    const float* bd1    = (const float*)d_in[12];
    const float* Wd2    = (const float*)d_in[13];
    const float* bd2    = (const float*)d_in[14];
    float* out          = (float*)d_out;

    const int N = in_sizes[0] / F;        // 100000
    const int E = in_sizes[1] / 2;        // 1600000
    const int P = in_sizes[2] / NVA;      // 8192

    const int* edge_src = eidx;
    const int* edge_dst = eidx + E;

    // workspace carve (256B aligned); deg+S+c first -> one zeroing memset
    size_t off = 0;
    auto carve = [&](size_t bytes) -> void* {
        void* ptr = (char*)d_ws + off;
        off += (bytes + 255) & ~(size_t)255;
        return ptr;
    };
    int*   deg    = (int*)carve((size_t)N * 4);
    float* S      = (float*)carve((size_t)NVA * N * 4);
    float* c      = (float*)carve((size_t)NVA * N * 4);
    const size_t zbytes = off;                       // zero deg + S + c in one memset
    int*   rs     = (int*)carve((size_t)(N + 1) * 4);
    int*   cursor = (int*)carve((size_t)N * 4);
    int*   csr    = (int*)carve((size_t)E * 4);
    int*   bsum   = (int*)carve(128 * 4);
    float* feat0  = (float*)carve((size_t)N * F * 4);
    float* featB  = (float*)carve((size_t)N * F * 4);
    float* agg    = (float*)carve((size_t)N * F * 4);
    float* pp_all = (float*)carve((size_t)NVA * P * 4);
    float* matsA  = (float*)carve(72 * 4);
    float* matsC  = (float*)carve(72 * 4);
    float* prevs  = (float*)carve(NVA * 4);
    (void)ws_size;

    const int nbScan   = (N + 1023) / 1024;                 // 98
    const int Ehalf    = E / 2;
    const int blkEh    = (Ehalf + 255) / 256;
    const int blkE2    = (E - Ehalf + 255) / 256;
    const int blkAgg   = (N + 3) / 4;
    const int blkLin   = (N + 31) / 32;
    const int bpv      = (P + 31) / 32;                     // 256 blocks per variant
    const int blkN     = (N + 255) / 256;

    (void)hipMemsetAsync(d_ws, 0, zbytes, stream);

    // CSR build
    k_hist <<<(E + 255) / 256, 256, 0, stream>>>(edge_dst, deg, E);
    k_scan1<<<nbScan, 256, 0, stream>>>(deg, rs, bsum, N);
    k_scan2<<<1, 128, 0, stream>>>(bsum, nbScan);
    k_scan3<<<nbScan, 256, 0, stream>>>(rs, bsum, cursor, N, E);
    k_fill <<<blkEh, 256, 0, stream>>>(edge_src, edge_dst, cursor, csr, 0, Ehalf);
    k_fill <<<blkE2, 256, 0, stream>>>(edge_src, edge_dst, cursor, csr, Ehalf, E);

    // first encoder: feat0 = relu(agg(x)@W1 + x@Wself1 + b1)
    k_agg   <<<blkAgg, 256, 0, stream>>>(x, rs, csr, agg, N);
    k_linear<<<blkLin, 256, 0, stream>>>(agg, x, W1, Wself1, b1, feat0, N);

    // Second-encoder chain is variant-independent -> compute once; decode both
    // variants per activity. feat buffers alternate feat0/featB (feat0's data
    // is dead after the a=0 GCN consumes it).
    const float* cur = feat0;
    for (int a = 0; a < ACTS; ++a) {
        k_decode2<<<2 * bpv, 256, 0, stream>>>(cur, places, srcs, dsts, a,
                                               Wd1, bd1, Wd2, bd2, pp_all, P, bpv);
        if (a < ACTS - 1) {  // last GCN's output is never read -> skip
            float* nxt = (cur == feat0) ? featB : feat0;
            k_agg   <<<blkAgg, 256, 0, stream>>>(cur, rs, csr, agg, N);
            k_linear<<<blkLin, 256, 0, stream>>>(agg, cur, W2, Wself2, b2, nxt, N);
            cur = nxt;
        }
    }

    // scatter pipeline (parallel)
    k_sc_scatter<<<(NVA * P + 255) / 256, 256, 0, stream>>>(pp_all, places, S, c, P, N);
    k_sc_mats   <<<VARIANTS * 36, 256, 0, stream>>>(S, c, places, matsA, matsC, P, N);
    k_sc_prev   <<<1, 64, 0, stream>>>(matsA, matsC, prevs);
    k_out       <<<blkN, 256, 0, stream>>>(S, c, prevs, out, N);
}

// Round 16
// 1580.121 us; speedup vs baseline: 1.9944x; 1.0106x over previous
//
#include <hip/hip_runtime.h>
#include <hip/hip_bf16.h>

#define F 64
#define VARIANTS 2
#define ACTS 6
#define NVA (VARIANTS * ACTS)

// ---------------- CSR build ----------------

__global__ void k_hist(const int* __restrict__ dst, int* __restrict__ deg, int e) {
    int i = blockIdx.x * blockDim.x + threadIdx.x;
    if (i < e) atomicAdd(&deg[dst[i]], 1);
}

__global__ void k_scan1(const int* __restrict__ deg, int* __restrict__ rs,
                        int* __restrict__ bsum, int n) {
    __shared__ int sh[256];
    const int tid = threadIdx.x;
    const int base = blockIdx.x * 1024 + tid * 4;
    int v0 = (base + 0 < n) ? deg[base + 0] : 0;
    int v1 = (base + 1 < n) ? deg[base + 1] : 0;
    int v2 = (base + 2 < n) ? deg[base + 2] : 0;
    int v3 = (base + 3 < n) ? deg[base + 3] : 0;
    const int tsum = v0 + v1 + v2 + v3;
    sh[tid] = tsum;
    __syncthreads();
    for (int off = 1; off < 256; off <<= 1) {
        int t = (tid >= off) ? sh[tid - off] : 0;
        __syncthreads();
        sh[tid] += t;
        __syncthreads();
    }
    int excl = sh[tid] - tsum;  // exclusive prefix within block
    if (base + 0 < n) rs[base + 0] = excl; excl += v0;
    if (base + 1 < n) rs[base + 1] = excl; excl += v1;
    if (base + 2 < n) rs[base + 2] = excl; excl += v2;
    if (base + 3 < n) rs[base + 3] = excl;
    if (tid == 255) bsum[blockIdx.x] = sh[255];
}

__global__ void k_scan2(int* __restrict__ bsum, int nb) {
    __shared__ int sh[128];
    const int tid = threadIdx.x;
    int v = (tid < nb) ? bsum[tid] : 0;
    sh[tid] = v;
    __syncthreads();
    for (int off = 1; off < 128; off <<= 1) {
        int t = (tid >= off) ? sh[tid - off] : 0;
        __syncthreads();
        sh[tid] += t;
        __syncthreads();
    }
    if (tid < nb) bsum[tid] = sh[tid] - v;  // exclusive
}

__global__ void k_scan3(int* __restrict__ rs, const int* __restrict__ bsum,
                        int* __restrict__ cursor, int n, int total) {
    const int base = blockIdx.x * 1024 + threadIdx.x * 4;
    const int off = bsum[blockIdx.x];
    #pragma unroll
    for (int j = 0; j < 4; ++j) {
        int i = base + j;
        if (i < n) {
            int v = rs[i] + off;
            rs[i] = v;
            cursor[i] = v;
        }
    }
    if (blockIdx.x == 0 && threadIdx.x == 0) rs[n] = total;
}

// split-range fill (two ~64 µs dispatches for profiler attribution)
__global__ void k_fill(const int* __restrict__ src, const int* __restrict__ dst,
                       int* __restrict__ cursor, int* __restrict__ csr, int e0, int e1) {
    int i = e0 + blockIdx.x * blockDim.x + threadIdx.x;
    if (i < e1) {
        int pos = atomicAdd(&cursor[dst[i]], 1);
        csr[pos] = src[i];
    }
}

// ---------------- GCN aggregate ----------------
__global__ __launch_bounds__(256) void k_agg(
    const float* __restrict__ hin, const int* __restrict__ rs,
    const int* __restrict__ csr, float* __restrict__ agg, int n)
{
    const int tid = threadIdx.x;
    const int lane = tid & 63;
    const int nd = blockIdx.x * 4 + (tid >> 6);
    if (nd >= n) return;
    const int beg = rs[nd], end = rs[nd + 1];
    const int sub = lane >> 4;   // neighbor subgroup
    const int f4  = lane & 15;   // float4 chunk within row
    float ax = 0.f, ay = 0.f, az = 0.f, aw = 0.f;
    for (int cb = beg + sub; cb < end; cb += 4) {
        const int s = csr[cb];
        const float4 v = ((const float4*)(hin + (size_t)s * F))[f4];
        ax += v.x; ay += v.y; az += v.z; aw += v.w;
    }
    #pragma unroll
    for (int o = 16; o <= 32; o <<= 1) {
        ax += __shfl_xor(ax, o);
        ay += __shfl_xor(ay, o);
        az += __shfl_xor(az, o);
        aw += __shfl_xor(aw, o);
    }
    if (sub == 0) {
        float4 r; r.x = ax; r.y = ay; r.z = az; r.w = aw;
        ((float4*)(agg + (size_t)nd * F))[f4] = r;
    }
}

// ---------------- fused linear: out = relu(agg@W + h@Wself + b) ----------------
// K-chunked (32 weights live at a time) to avoid VGPR spill; accumulation order
// identical to the unchunked version (agg k=0..63, then hin k=0..63).
__global__ __launch_bounds__(256) void k_linear(
    const float* __restrict__ agg, const float* __restrict__ hin,
    const float* __restrict__ W, const float* __restrict__ Wself,
    const float* __restrict__ bias, float* __restrict__ out, int n)
{
    const int lane = threadIdx.x & 63;
    const int wv = blockIdx.x * 4 + (threadIdx.x >> 6);
    const int base = wv * 8;
    const float bf = bias[lane];
    float acc[8];
    #pragma unroll
    for (int t = 0; t < 8; ++t) acc[t] = bf;

    for (int src = 0; src < 2; ++src) {
        const float* __restrict__ mat = src ? hin : agg;
        const float* __restrict__ Wm  = src ? Wself : W;
        for (int k0 = 0; k0 < 64; k0 += 32) {
            float wch[32];
            #pragma unroll
            for (int k = 0; k < 32; ++k) wch[k] = Wm[(k0 + k) * F + lane];
            #pragma unroll
            for (int t = 0; t < 8; ++t) {
                const int nd = base + t;
                if (nd < n) {
                    const float4* __restrict__ r4 =
                        (const float4*)(mat + (size_t)nd * F + k0);
                    float a = acc[t];
                    #pragma unroll
                    for (int q = 0; q < 8; ++q) {
                        const float4 v = r4[q];
                        a = fmaf(v.x, wch[q * 4 + 0], a);
                        a = fmaf(v.y, wch[q * 4 + 1], a);
                        a = fmaf(v.z, wch[q * 4 + 2], a);
                        a = fmaf(v.w, wch[q * 4 + 3], a);
                    }
                    acc[t] = a;
                }
            }
        }
    }
    #pragma unroll
    for (int t = 0; t < 8; ++t) {
        const int nd = base + t;
        if (nd < n) out[(size_t)nd * F + lane] = fmaxf(acc[t], 0.f);
    }
}

// ---------------- decode (both variants in one launch) ----------------
// Same K-chunking as k_linear (32 weights live); accumulation order unchanged.
__global__ __launch_bounds__(256) void k_decode2(
    const float* __restrict__ feat,
    const int* __restrict__ places, const int* __restrict__ srcs, const int* __restrict__ dsts,
    int a, const float* __restrict__ Wd1, const float* __restrict__ bd1,
    const float* __restrict__ Wd2, const float* __restrict__ bd2,
    float* __restrict__ pp_all, int nT, int bpv)
{
    const int v   = blockIdx.x / bpv;
    const int blk = blockIdx.x % bpv;
    const size_t ofs = ((size_t)v * ACTS + a) * nT;
    const int* __restrict__ pi = places + ofs;
    const int* __restrict__ si = srcs   + ofs;
    const int* __restrict__ di = dsts   + ofs;
    float* __restrict__ ppv = pp_all + ofs;

    const int lane = threadIdx.x & 63;
    const int wv = blk * 4 + (threadIdx.x >> 6);
    const int base = wv * 8;
    if (base >= nT) return;
    float acc[8];
    const float b0 = bd1[lane];
    #pragma unroll
    for (int t = 0; t < 8; ++t) acc[t] = b0;

    for (int g = 0; g < 3; ++g) {
        const int* __restrict__ idx = (g == 0) ? pi : (g == 1) ? si : di;
        const float* __restrict__ Wg = Wd1 + (size_t)g * 64 * F;
        for (int k0 = 0; k0 < 64; k0 += 32) {
            float wch[32];
            #pragma unroll
            for (int k = 0; k < 32; ++k) wch[k] = Wg[(k0 + k) * F + lane];
            #pragma unroll
            for (int t = 0; t < 8; ++t) {
                const int tri = base + t;
                if (tri < nT) {
                    const int nd = idx[tri];  // wave-uniform
                    const float4* __restrict__ r4 =
                        (const float4*)(feat + (size_t)nd * F + k0);
                    float a2 = acc[t];
                    #pragma unroll
                    for (int q = 0; q < 8; ++q) {
                        const float4 vv = r4[q];
                        a2 = fmaf(vv.x, wch[q * 4 + 0], a2);
                        a2 = fmaf(vv.y, wch[q * 4 + 1], a2);
                        a2 = fmaf(vv.z, wch[q * 4 + 2], a2);
                        a2 = fmaf(vv.w, wch[q * 4 + 3], a2);
                    }
                    acc[t] = a2;
                }
            }
        }
    }
    const float w2 = Wd2[lane];
    const float b2v = bd2[0];
    #pragma unroll
    for (int t = 0; t < 8; ++t) {
        const int tri = base + t;
        if (tri < nT) {
            float h = fmaxf(acc[t], 0.f);
            float vv = h * w2;
            #pragma unroll
            for (int o = 32; o; o >>= 1) vv += __shfl_xor(vv, o);
            if (lane == 0) {
                float z = vv + b2v;
                ppv[tri] = fminf(z, 0.f) - log1pf(expf(-fabsf(z)));
            }
        }
    }
}

// ---------------- scatter pipeline (algebraic, fully parallel) ----------------

__global__ void k_sc_scatter(const float* __restrict__ pp_all, const int* __restrict__ places,
                             float* __restrict__ S, float* __restrict__ c, int nP, int n) {
    int gid = blockIdx.x * blockDim.x + threadIdx.x;
    if (gid < NVA * nP) {
        int va = gid / nP;
        int p = places[gid];
        atomicAdd(&S[(size_t)va * n + p], pp_all[gid]);
        atomicAdd(&c[(size_t)va * n + p], 1.0f);
    }
}

__global__ __launch_bounds__(256) void k_sc_mats(
    const float* __restrict__ S, const float* __restrict__ c,
    const int* __restrict__ places,
    float* __restrict__ matsA, float* __restrict__ matsC, int nP, int n)
{
    const int bx = blockIdx.x;          // v*36 + a*6 + b
    const int v = bx / 36;
    const int a = (bx / 6) % 6;
    const int b = bx % 6;
    if (b > a) return;
    const int* __restrict__ p = places + (size_t)(v * ACTS + a) * nP;
    const float* __restrict__ Sb = S + (size_t)(v * ACTS + b) * n;
    const float* __restrict__ cb = c + (size_t)(v * ACTS + b) * n;
    float sS = 0.f, sC = 0.f;
    for (int i = threadIdx.x; i < nP; i += 256) {
        const int idx = p[i];
        sS += Sb[idx];
        sC += cb[idx];
    }
    __shared__ float shS[4], shC[4];
    #pragma unroll
    for (int o = 32; o; o >>= 1) { sS += __shfl_down(sS, o); sC += __shfl_down(sC, o); }
    const int lane = threadIdx.x & 63, w = threadIdx.x >> 6;
    if (lane == 0) { shS[w] = sS; shC[w] = sC; }
    __syncthreads();
    if (threadIdx.x == 0) {
        matsA[bx] = shS[0] + shS[1] + shS[2] + shS[3];
        matsC[bx] = shC[0] + shC[1] + shC[2] + shC[3];
    }
}

__global__ void k_sc_prev(const float* __restrict__ matsA, const float* __restrict__ matsC,
                          float* __restrict__ prevs) {
    const int v = threadIdx.x;
    if (v >= VARIANTS) return;
    float pl[ACTS];
    float prev = 0.f;
    #pragma unroll
    for (int a = 0; a < ACTS; ++a) {
        float s = 0.f;
        #pragma unroll
        for (int b = 0; b < ACTS; ++b) {
            if (b <= a) s += matsA[v * 36 + a * 6 + b];
            if (b < a)  s += matsC[v * 36 + a * 6 + b] * pl[b];
        }
        prev += s;
        pl[a] = prev;
        prevs[v * ACTS + a] = prev;
    }
}

__global__ void k_out(const float* __restrict__ S, const float* __restrict__ c,
                      const float* __restrict__ prevs, float* __restrict__ out, int n) {
    int i = blockIdx.x * blockDim.x + threadIdx.x;
    if (i < n) {
        float acc = 0.f;
        #pragma unroll
        for (int va = 0; va < NVA; ++va)
            acc += S[(size_t)va * n + i] + c[(size_t)va * n + i] * prevs[va];
        out[i] = acc;
    }
}

// ---------------- launch ----------------

extern "C" void kernel_launch(void* const* d_in, const int* in_sizes, int n_in,
                              void* d_out, int out_size, void* d_ws, size_t ws_size,
                              hipStream_t stream) {
    const float* x      = (const float*)d_in[0];
    const int*   eidx   = (const int*)d_in[1];
    const int*   places = (const int*)d_in[2];
    const int*   srcs   = (const int*)d_in[3];
    const int*   dsts   = (const int*)d_in[4];
    const float* W1     = (const float*)d_in[5];
    const float* Wself1 = (const float*)d_in[6];
    const float* b1     = (const float*)d_in[7];
    const float* W2     = (const float*)d_in[8];
    const float* Wself2 = (const float*)d_in[9];
    const float* b2     = (const float*)d_in[10];
    const float* Wd1    = (const float*)d_in[11];
    const float* bd1    = (const float*)d_in[12];
    const float* Wd2    = (const float*)d_in[13];
    const float* bd2    = (const float*)d_in[14];
    float* out          = (float*)d_out;

    const int N = in_sizes[0] / F;        // 100000
    const int E = in_sizes[1] / 2;        // 1600000
    const int P = in_sizes[2] / NVA;      // 8192

    const int* edge_src = eidx;
    const int* edge_dst = eidx + E;

    // workspace carve (256B aligned); deg+S+c first -> one zeroing memset
    size_t off = 0;
    auto carve = [&](size_t bytes) -> void* {
        void* ptr = (char*)d_ws + off;
        off += (bytes + 255) & ~(size_t)255;
        return ptr;
    };
    int*   deg    = (int*)carve((size_t)N * 4);
    float* S      = (float*)carve((size_t)NVA * N * 4);
    float* c      = (float*)carve((size_t)NVA * N * 4);
    const size_t zbytes = off;                       // zero deg + S + c in one memset
    int*   rs     = (int*)carve((size_t)(N + 1) * 4);
    int*   cursor = (int*)carve((size_t)N * 4);
    int*   csr    = (int*)carve((size_t)E * 4);
    int*   bsum   = (int*)carve(128 * 4);
    float* feat0  = (float*)carve((size_t)N * F * 4);
    float* featB  = (float*)carve((size_t)N * F * 4);
    float* agg    = (float*)carve((size_t)N * F * 4);
    float* pp_all = (float*)carve((size_t)NVA * P * 4);
    float* matsA  = (float*)carve(72 * 4);
    float* matsC  = (float*)carve(72 * 4);
    float* prevs  = (float*)carve(NVA * 4);
    (void)ws_size;

    const int nbScan   = (N + 1023) / 1024;                 // 98
    const int Ehalf    = E / 2;
    const int blkEh    = (Ehalf + 255) / 256;
    const int blkE2    = (E - Ehalf + 255) / 256;
    const int blkAgg   = (N + 3) / 4;
    const int blkLin   = (N + 31) / 32;
    const int bpv      = (P + 31) / 32;                     // 256 blocks per variant
    const int blkN     = (N + 255) / 256;

    (void)hipMemsetAsync(d_ws, 0, zbytes, stream);

    // CSR build
    k_hist <<<(E + 255) / 256, 256, 0, stream>>>(edge_dst, deg, E);
    k_scan1<<<nbScan, 256, 0, stream>>>(deg, rs, bsum, N);
    k_scan2<<<1, 128, 0, stream>>>(bsum, nbScan);
    k_scan3<<<nbScan, 256, 0, stream>>>(rs, bsum, cursor, N, E);
    k_fill <<<blkEh, 256, 0, stream>>>(edge_src, edge_dst, cursor, csr, 0, Ehalf);
    k_fill <<<blkE2, 256, 0, stream>>>(edge_src, edge_dst, cursor, csr, Ehalf, E);

    // first encoder: feat0 = relu(agg(x)@W1 + x@Wself1 + b1)
    k_agg   <<<blkAgg, 256, 0, stream>>>(x, rs, csr, agg, N);
    k_linear<<<blkLin, 256, 0, stream>>>(agg, x, W1, Wself1, b1, feat0, N);

    // Second-encoder chain is variant-independent -> compute once; decode both
    // variants per activity. feat buffers alternate feat0/featB.
    const float* cur = feat0;
    for (int a = 0; a < ACTS; ++a) {
        k_decode2<<<2 * bpv, 256, 0, stream>>>(cur, places, srcs, dsts, a,
                                               Wd1, bd1, Wd2, bd2, pp_all, P, bpv);
        if (a < ACTS - 1) {  // last GCN's output is never read -> skip
            float* nxt = (cur == feat0) ? featB : feat0;
            k_agg   <<<blkAgg, 256, 0, stream>>>(cur, rs, csr, agg, N);
            k_linear<<<blkLin, 256, 0, stream>>>(agg, cur, W2, Wself2, b2, nxt, N);
            cur = nxt;
        }
    }

    // scatter pipeline (parallel)
    k_sc_scatter<<<(NVA * P + 255) / 256, 256, 0, stream>>>(pp_all, places, S, c, P, N);
    k_sc_mats   <<<VARIANTS * 36, 256, 0, stream>>>(S, c, places, matsA, matsC, P, N);
    k_sc_prev   <<<1, 64, 0, stream>>>(matsA, matsC, prevs);
    k_out       <<<blkN, 256, 0, stream>>>(S, c, prevs, out, N);
}